// Round 17
// baseline (206.155 us; speedup 1.0000x reference)
//
#include <hip/hip_runtime.h>
#include <hip/hip_bf16.h>

#define CS 384
#define CH 32
#define CZ 128
#define LL 384
#define NL 1536   // N*L
#define EPS 1e-5f

typedef float v4f __attribute__((ext_vector_type(4)));
typedef short s8v __attribute__((ext_vector_type(8)));          // 8 bf16 (MFMA A/B frag)
typedef unsigned short u8s __attribute__((ext_vector_type(8))); // 8 bf16 bits

static __device__ __forceinline__ unsigned short f2bf(float x) {
    unsigned int b = __float_as_uint(x);
    b += 0x7FFFu + ((b >> 16) & 1u);        // round-to-nearest-even
    return (unsigned short)(b >> 16);
}

// ---------------- Kernel 1: INSTRUMENTATION — R14/R16 prep body run 8x -------
// rep-loop with opaque'd s/Wo pointers (no cross-rep CSE); all stores
// idempotent -> output identical. prep_time = (total - 85.6)/7.
__global__ __launch_bounds__(256, 2) void k_prep8(
    const float* __restrict__ s_in, const float* __restrict__ g, const float* __restrict__ be,
    const float* __restrict__ W1, const float* __restrict__ pb1,
    const float* __restrict__ W2, const float* __restrict__ pb2,
    const float* __restrict__ Wo_in,
    unsigned short* __restrict__ Bf, unsigned short* __restrict__ Mf)
{
    const int blk = blockIdx.x;     // 0..383
    const int r0  = blk * 4;
    const int t   = threadIdx.x;

    __shared__ float sn[4][392];
    __shared__ float Afl[4][CH];
    __shared__ __align__(16) float Msub[4 * 32 * 128];   // 64 KB

    for (int rep = 0; rep < 8; ++rep) {
        __syncthreads();   // prior rep's Msub pack / LDS readers done

        // opaque the root pointers: forces full reload + recompute per rep
        unsigned long long ps = (unsigned long long)s_in;
        unsigned long long pw = (unsigned long long)Wo_in;
        asm volatile("" : "+v"(ps), "+v"(pw));
        const float* s  = (const float*)ps;
        const float* Wo = (const float*)pw;

        // ---- Phase A: LayerNorm, wave w = row r0+w ----
        {
            const int w = t >> 6, lane = t & 63;
            const float* srow = s + (size_t)(r0 + w) * CS;
            float x[6];
            #pragma unroll
            for (int k = 0; k < 6; ++k) x[k] = srow[lane + k * 64];
            float p = x[0] + x[1] + x[2] + x[3] + x[4] + x[5];
            #pragma unroll
            for (int m = 1; m < 64; m <<= 1) p += __shfl_xor(p, m);
            const float mu = p * (1.0f / CS);
            float q = 0.f;
            #pragma unroll
            for (int k = 0; k < 6; ++k) { float d = x[k] - mu; q += d * d; }
            #pragma unroll
            for (int m = 1; m < 64; m <<= 1) q += __shfl_xor(q, m);
            const float rstd = rsqrtf(q * (1.0f / CS) + EPS);
            #pragma unroll
            for (int k = 0; k < 6; ++k) {
                const int c = lane + k * 64;
                sn[w][c] = (x[k] - mu) * rstd * g[c] + be[c];
            }
        }
        __syncthreads();

        // ---- Phase B: matvec, one output per thread ----
        {
            const int h = t & 31, mat = (t >> 5) & 1, rw = t >> 6;
            const float* W = mat ? W2 : W1;
            const float* snr = sn[rw];
            float acc = 0.f;
            #pragma unroll 8
            for (int c = 0; c < CS; ++c)
                acc += snr[c] * W[c * CH + h];
            acc += mat ? pb2[h] : pb1[h];
            if (!mat) {
                Afl[rw][h] = acc;
            } else {
                const int row = r0 + rw;
                const int n = row / LL, jr = row % LL;
                const int jt = jr >> 4, l16 = jr & 15;
                Bf[(((size_t)(n * 24 + jt)) * 64 + l16 + 16 * (h >> 3)) * 8 + (h & 7)] = f2bf(acc);
            }
        }
        __syncthreads();

        // ---- Phase C: M = Afl @ Wo ----
        const v4f* Wo4 = (const v4f*)Wo;       // 1024 v4f per c-row
        #pragma unroll
        for (int it = 0; it < 4; ++it) {
            const int col = t + it * 256;      // col = d*32 + zq
            v4f acc[4];
            #pragma unroll
            for (int r = 0; r < 4; ++r) acc[r] = (v4f)(0.f);
            #pragma unroll 8
            for (int c = 0; c < CH; ++c) {
                const v4f wv = Wo4[(size_t)c * 1024 + col];
                #pragma unroll
                for (int r = 0; r < 4; ++r)
                    acc[r] += Afl[r][c] * wv;
            }
            #pragma unroll
            for (int r = 0; r < 4; ++r)
                *((v4f*)&Msub[r * 4096 + col * 4]) = acc[r];   // flat = r*4096 + d*128 + zq*4
        }
        __syncthreads();

        #pragma unroll
        for (int i = 0; i < 8; ++i) {
            const int item = t + i * 256;          // 0..2047
            const int l  = item & 63;
            const int zt = (item >> 6) & 7;
            const int rr = item >> 9;
            const int gq = l >> 4;
            const int z  = zt * 16 + (l & 15);
            u8s o;
            #pragma unroll
            for (int e = 0; e < 8; ++e)
                o[e] = f2bf(Msub[rr * 4096 + (gq * 8 + e) * 128 + z]);
            *(u8s*)(Mf + (((size_t)(r0 + rr) * 8 + zt) * 64 + l) * 8) = o;
        }
    }
}

// ---------------- Kernel 2: MFMA k_out with LDS-bounce (byte-identical R16) --
__global__ __launch_bounds__(256, 3) void k_out(
    const unsigned short* __restrict__ Bf, const unsigned short* __restrict__ Mf,
    const float* __restrict__ bo, float* __restrict__ out)
{
    const int r = blockIdx.x;
    const int t = threadIdx.x;
    const int l = t & 63, w = t >> 6;
    const int g = l >> 4, c16 = l & 15;
    const int li = l & 31, hi2 = l >> 5;
    const int n = r / LL;

    __shared__ __align__(16) float lds[4][2048];   // 8 KB per wave

    s8v mf[8];
    {
        const s8v* Mfr = (const s8v*)(Mf + (size_t)r * 8 * 64 * 8);
        #pragma unroll
        for (int zt = 0; zt < 8; ++zt) mf[zt] = Mfr[zt * 64 + l];
    }
    s8v af[6];
    {
        const s8v* Bfn = (const s8v*)(Bf + (size_t)n * 24 * 64 * 8);
        #pragma unroll
        for (int i = 0; i < 6; ++i) af[i] = Bfn[(w + i * 4) * 64 + l];
    }
    v4f bov[8];
    #pragma unroll
    for (int zt = 0; zt < 8; ++zt) bov[zt] = *(const v4f*)(bo + zt * 16 + g * 4);

    char* myl = (char*)lds[w];
    v4f* outv = (v4f*)(out + (size_t)r * LL * CZ);   // 32 v4f per j-row

    #pragma unroll
    for (int i = 0; i < 6; ++i) {
        const int jt = w + i * 4;

        #pragma unroll
        for (int zt = 0; zt < 8; ++zt) {
            v4f d = __builtin_amdgcn_mfma_f32_16x16x32_bf16(mf[zt], af[i], (v4f)(0.f), 0, 0, 0);
            d += bov[zt];
            const int byte = (c16 << 9) + (((zt << 6) + (g << 4)) ^ ((c16 & 7) << 4));
            *(v4f*)(myl + byte) = d;
        }
        asm volatile("s_waitcnt lgkmcnt(0)" ::: "memory");

        #pragma unroll
        for (int i2 = 0; i2 < 8; ++i2) {
            const int rr = 2 * i2 + hi2;
            const int byte = (rr << 9) + (((li << 4)) ^ ((rr & 7) << 4));
            const v4f v = *(const v4f*)(myl + byte);
            outv[(size_t)(jt * 16 + rr) * 32 + li] = v;
        }
    }
}

extern "C" void kernel_launch(void* const* d_in, const int* in_sizes, int n_in,
                              void* d_out, int out_size, void* d_ws, size_t ws_size,
                              hipStream_t stream) {
    const float* s  = (const float*)d_in[0];
    const float* g  = (const float*)d_in[1];
    const float* be = (const float*)d_in[2];
    const float* W1 = (const float*)d_in[3];
    const float* b1 = (const float*)d_in[4];
    const float* W2 = (const float*)d_in[5];
    const float* b2 = (const float*)d_in[6];
    const float* Wo = (const float*)d_in[7];
    const float* bo = (const float*)d_in[8];
    float* out = (float*)d_out;

    // ws layout (bytes): Bf bf16 [0, 98304) | Mf bf16 [98304, +12582912)
    if (ws_size < 98304u + 12582912u) return;  // fail visibly, no UB
    unsigned short* Bf = (unsigned short*)d_ws;
    unsigned short* Mf = (unsigned short*)((char*)d_ws + 98304);

    k_prep8<<<NL / 4, 256, 0, stream>>>(s, g, be, W1, b1, W2, b2, Wo, Bf, Mf);
    k_out  <<<NL, 256, 0, stream>>>(Bf, Mf, bo, out);
}

// Round 18
// 100.949 us; speedup vs baseline: 2.0422x; 2.0422x over previous
//
#include <hip/hip_runtime.h>
#include <hip/hip_bf16.h>

#define CS 384
#define CH 32
#define CZ 128
#define LL 384
#define NL 1536   // N*L
#define EPS 1e-5f

typedef float v4f __attribute__((ext_vector_type(4)));
typedef short s8v __attribute__((ext_vector_type(8)));          // 8 bf16 (MFMA A/B frag)
typedef unsigned short u8s __attribute__((ext_vector_type(8))); // 8 bf16 bits

static __device__ __forceinline__ unsigned short f2bf(float x) {
    unsigned int b = __float_as_uint(x);
    b += 0x7FFFu + ((b >> 16) & 1u);        // round-to-nearest-even
    return (unsigned short)(b >> 16);
}

// ---------------- Kernel 1: prep, z-quarter split for occupancy --------------
// Grid 1536 = 384 row-groups x 4 z-quarters. Each block: LN(4 rows) + A-matvec
// (duplicated across quarters; B-matvec+Bf only on quarter 0) + M = A@Wo for
// its 32-z slice -> bf16 Msub (9 KB LDS) -> Mf frags. LDS ~16 KB -> 4 blocks/CU
// (R17 counters: Occupancy 15.7%, VALUBusy 28% -> was grid/latency-bound).
__global__ __launch_bounds__(256, 4) void k_prep(
    const float* __restrict__ s, const float* __restrict__ g, const float* __restrict__ be,
    const float* __restrict__ W1, const float* __restrict__ pb1,
    const float* __restrict__ W2, const float* __restrict__ pb2,
    const float* __restrict__ Wo,
    unsigned short* __restrict__ Bf, unsigned short* __restrict__ Mf)
{
    const int blk = blockIdx.x;     // 0..1535
    const int rg  = blk >> 2;       // row-group 0..383
    const int qz  = blk & 3;        // z-quarter 0..3
    const int r0  = rg * 4;
    const int t   = threadIdx.x;

    __shared__ float sn[4][392];
    __shared__ float Afl[4][CH];
    __shared__ __align__(8) unsigned short MsubS[4 * 32 * 36];   // bf16 [rr][d][36]

    // ---- Phase A: LayerNorm, wave w = row r0+w ----
    {
        const int w = t >> 6, lane = t & 63;
        const float* srow = s + (size_t)(r0 + w) * CS;
        float x[6];
        #pragma unroll
        for (int k = 0; k < 6; ++k) x[k] = srow[lane + k * 64];
        float p = x[0] + x[1] + x[2] + x[3] + x[4] + x[5];
        #pragma unroll
        for (int m = 1; m < 64; m <<= 1) p += __shfl_xor(p, m);
        const float mu = p * (1.0f / CS);
        float q = 0.f;
        #pragma unroll
        for (int k = 0; k < 6; ++k) { float d = x[k] - mu; q += d * d; }
        #pragma unroll
        for (int m = 1; m < 64; m <<= 1) q += __shfl_xor(q, m);
        const float rstd = rsqrtf(q * (1.0f / CS) + EPS);
        #pragma unroll
        for (int k = 0; k < 6; ++k) {
            const int c = lane + k * 64;
            sn[w][c] = (x[k] - mu) * rstd * g[c] + be[c];
        }
    }
    __syncthreads();

    // ---- Phase B: matvec. A always; B (+Bf store) only on quarter 0 ----
    {
        const int h = t & 31, mat = (t >> 5) & 1, rw = t >> 6;
        if (!mat) {
            const float* snr = sn[rw];
            float acc = 0.f;
            #pragma unroll 8
            for (int c = 0; c < CS; ++c)
                acc += snr[c] * W1[c * CH + h];
            Afl[rw][h] = acc + pb1[h];
        } else if (qz == 0) {
            const float* snr = sn[rw];
            float acc = 0.f;
            #pragma unroll 8
            for (int c = 0; c < CS; ++c)
                acc += snr[c] * W2[c * CH + h];
            acc += pb2[h];
            const int row = r0 + rw;
            const int n = row / LL, jr = row % LL;
            const int jt = jr >> 4, l16 = jr & 15;
            Bf[(((size_t)(n * 24 + jt)) * 64 + l16 + 16 * (h >> 3)) * 8 + (h & 7)] = f2bf(acc);
        }
    }
    __syncthreads();

    // ---- Phase C: M slice = Afl @ Wo[:, :, qz*32 .. +32) ----
    {
        const v4f* Wo4 = (const v4f*)Wo;        // 1024 v4f per c-row
        const int d   = t >> 3;                 // 0..31
        const int zq8 = t & 7;                  // z-quad within quarter
        const int col = d * 32 + (qz << 3) + zq8;
        v4f acc[4];
        #pragma unroll
        for (int r = 0; r < 4; ++r) acc[r] = (v4f)(0.f);
        #pragma unroll 8
        for (int c = 0; c < CH; ++c) {
            const v4f wv = Wo4[(size_t)c * 1024 + col];
            #pragma unroll
            for (int r = 0; r < 4; ++r)
                acc[r] += Afl[r][c] * wv;
        }
        #pragma unroll
        for (int r = 0; r < 4; ++r) {
            ushort4 hh;
            hh.x = f2bf(acc[r].x); hh.y = f2bf(acc[r].y);
            hh.z = f2bf(acc[r].z); hh.w = f2bf(acc[r].w);
            *(ushort4*)&MsubS[(r * 32 + d) * 36 + zq8 * 4] = hh;
        }
    }
    __syncthreads();

    // ---- pack Mf for zt in {2qz, 2qz+1}: 512 frag-items, 2 per thread ----
    #pragma unroll
    for (int i = 0; i < 2; ++i) {
        const int item = t + i * 256;           // 0..511
        const int l   = item & 63;
        const int ztl = (item >> 6) & 1;
        const int rr  = item >> 7;              // 0..3
        const int zt  = (qz << 1) + ztl;
        const int zloc = ztl * 16 + (l & 15);
        const int gq  = l >> 4;
        u8s o;
        #pragma unroll
        for (int e = 0; e < 8; ++e)
            o[e] = MsubS[(rr * 32 + gq * 8 + e) * 36 + zloc];
        *(u8s*)(Mf + (((size_t)(r0 + rr) * 8 + zt) * 64 + l) * 8) = o;
    }
}

// ---------------- Kernel 2: MFMA k_out with LDS-bounce (byte-identical R16) --
__global__ __launch_bounds__(256, 3) void k_out(
    const unsigned short* __restrict__ Bf, const unsigned short* __restrict__ Mf,
    const float* __restrict__ bo, float* __restrict__ out)
{
    const int r = blockIdx.x;
    const int t = threadIdx.x;
    const int l = t & 63, w = t >> 6;
    const int g = l >> 4, c16 = l & 15;
    const int li = l & 31, hi2 = l >> 5;
    const int n = r / LL;

    __shared__ __align__(16) float lds[4][2048];   // 8 KB per wave

    s8v mf[8];
    {
        const s8v* Mfr = (const s8v*)(Mf + (size_t)r * 8 * 64 * 8);
        #pragma unroll
        for (int zt = 0; zt < 8; ++zt) mf[zt] = Mfr[zt * 64 + l];
    }
    s8v af[6];
    {
        const s8v* Bfn = (const s8v*)(Bf + (size_t)n * 24 * 64 * 8);
        #pragma unroll
        for (int i = 0; i < 6; ++i) af[i] = Bfn[(w + i * 4) * 64 + l];
    }
    v4f bov[8];
    #pragma unroll
    for (int zt = 0; zt < 8; ++zt) bov[zt] = *(const v4f*)(bo + zt * 16 + g * 4);

    char* myl = (char*)lds[w];
    v4f* outv = (v4f*)(out + (size_t)r * LL * CZ);   // 32 v4f per j-row

    #pragma unroll
    for (int i = 0; i < 6; ++i) {
        const int jt = w + i * 4;

        #pragma unroll
        for (int zt = 0; zt < 8; ++zt) {
            v4f d = __builtin_amdgcn_mfma_f32_16x16x32_bf16(mf[zt], af[i], (v4f)(0.f), 0, 0, 0);
            d += bov[zt];
            const int byte = (c16 << 9) + (((zt << 6) + (g << 4)) ^ ((c16 & 7) << 4));
            *(v4f*)(myl + byte) = d;
        }
        asm volatile("s_waitcnt lgkmcnt(0)" ::: "memory");

        #pragma unroll
        for (int i2 = 0; i2 < 8; ++i2) {
            const int rr = 2 * i2 + hi2;
            const int byte = (rr << 9) + (((li << 4)) ^ ((rr & 7) << 4));
            const v4f v = *(const v4f*)(myl + byte);
            outv[(size_t)(jt * 16 + rr) * 32 + li] = v;
        }
    }
}

extern "C" void kernel_launch(void* const* d_in, const int* in_sizes, int n_in,
                              void* d_out, int out_size, void* d_ws, size_t ws_size,
                              hipStream_t stream) {
    const float* s  = (const float*)d_in[0];
    const float* g  = (const float*)d_in[1];
    const float* be = (const float*)d_in[2];
    const float* W1 = (const float*)d_in[3];
    const float* b1 = (const float*)d_in[4];
    const float* W2 = (const float*)d_in[5];
    const float* b2 = (const float*)d_in[6];
    const float* Wo = (const float*)d_in[7];
    const float* bo = (const float*)d_in[8];
    float* out = (float*)d_out;

    // ws layout (bytes): Bf bf16 [0, 98304) | Mf bf16 [98304, +12582912)
    if (ws_size < 98304u + 12582912u) return;  // fail visibly, no UB
    unsigned short* Bf = (unsigned short*)d_ws;
    unsigned short* Mf = (unsigned short*)((char*)d_ws + 98304);

    k_prep<<<NL, 256, 0, stream>>>(s, g, be, W1, b1, W2, b2, Wo, Bf, Mf);
    k_out <<<NL, 256, 0, stream>>>(Bf, Mf, bo, out);
}

// Round 20
// 85.550 us; speedup vs baseline: 2.4098x; 1.1800x over previous
//
#include <hip/hip_runtime.h>
#include <hip/hip_bf16.h>

#define CS 384
#define CH 32
#define CZ 128
#define LL 384
#define NL 1536   // N*L
#define EPS 1e-5f

typedef float v4f __attribute__((ext_vector_type(4)));
typedef short s8v __attribute__((ext_vector_type(8)));          // 8 bf16 (MFMA A/B frag)
typedef unsigned short u8s __attribute__((ext_vector_type(8))); // 8 bf16 bits

static __device__ __forceinline__ unsigned short f2bf(float x) {
    unsigned int b = __float_as_uint(x);
    b += 0x7FFFu + ((b >> 16) & 1u);        // round-to-nearest-even
    return (unsigned short)(b >> 16);
}

// ---------------- Kernel 1: LN + B = sn@W2+b2 -> Bf fragments ----------------
// 384 blocks x 256 thr, 4 rows/block. Bf layout (unchanged):
// Bf[((n*24+jt)*64 + l)*8 + e] = bf16( B[n, jt*16+(l&15), (l>>4)*8+e] )
__global__ __launch_bounds__(256) void k_bf(
    const float* __restrict__ s, const float* __restrict__ g, const float* __restrict__ be,
    const float* __restrict__ W2, const float* __restrict__ pb2,
    unsigned short* __restrict__ BfG)
{
    const int r0 = blockIdx.x * 4;
    const int t  = threadIdx.x;

    __shared__ float sn[4][392];
    __shared__ float part[4][2][32];

    // LN, wave per row
    {
        const int w = t >> 6, lane = t & 63;
        const float* srow = s + (size_t)(r0 + w) * CS;
        float x[6];
        #pragma unroll
        for (int k = 0; k < 6; ++k) x[k] = srow[lane + k * 64];
        float p = x[0] + x[1] + x[2] + x[3] + x[4] + x[5];
        #pragma unroll
        for (int m = 1; m < 64; m <<= 1) p += __shfl_xor(p, m);
        const float mu = p * (1.0f / CS);
        float q = 0.f;
        #pragma unroll
        for (int k = 0; k < 6; ++k) { float d = x[k] - mu; q += d * d; }
        #pragma unroll
        for (int m = 1; m < 64; m <<= 1) q += __shfl_xor(q, m);
        const float rstd = rsqrtf(q * (1.0f / CS) + EPS);
        #pragma unroll
        for (int k = 0; k < 6; ++k) {
            const int c = lane + k * 64;
            sn[w][c] = (x[k] - mu) * rstd * g[c] + be[c];
        }
    }
    __syncthreads();

    // matvec W2, c-halves
    {
        const int h = t & 31, ch = (t >> 5) & 1, rw = t >> 6;
        const float* snr = sn[rw];
        float acc = 0.f;
        const int c0 = ch * 192;
        #pragma unroll 8
        for (int c = c0; c < c0 + 192; ++c)
            acc += snr[c] * W2[c * CH + h];
        part[rw][ch][h] = acc;
    }
    __syncthreads();

    if (t < 128) {
        const int rw = t >> 5, h = t & 31;
        const float v = part[rw][0][h] + part[rw][1][h] + pb2[h];
        const int row = r0 + rw;
        const int n = row / LL, jr = row % LL;
        const int jt = jr >> 4, l16 = jr & 15;
        BfG[(((size_t)(n * 24 + jt)) * 64 + l16 + 16 * (h >> 3)) * 8 + (h & 7)] = f2bf(v);
    }
}

// ---------------- Kernel 2: per-r fused prep + MFMA out ----------------------
// Block = r (256 thr, 4 waves, 3 blocks/CU). In-block: LN(r) -> a = sn@W1+b1
// -> M = a@Wo (vectorized col-major, Wo 512 KB from L2) -> mf[8] per lane from
// Msub -> R16's exact out loop (af hoisted, MFMA, swizzled LDS bounce,
// contiguous 1024-B wave stores). No Mf global round-trip, no prep kernel.
__global__ __launch_bounds__(256, 3) void k_out_f(
    const float* __restrict__ s, const float* __restrict__ g, const float* __restrict__ be,
    const float* __restrict__ W1, const float* __restrict__ pb1,
    const float* __restrict__ Wo, const unsigned short* __restrict__ BfG,
    const float* __restrict__ bo, float* __restrict__ out)
{
    const int r = blockIdx.x;
    const int t = threadIdx.x;
    const int l = t & 63, w = t >> 6;
    const int g2 = l >> 4, c16 = l & 15;
    const int li = l & 31, hi2 = l >> 5;
    const int n = r / LL;

    __shared__ float sn[392];
    __shared__ float red[8];
    __shared__ float part[8][32];
    __shared__ float Afl[CH];
    __shared__ __align__(16) float Msub[4096];          // 16 KB  [d*128 + z]
    __shared__ __align__(16) float bounce[4][2048];     // 32 KB

    // ---- LN of row r (block-wide) ----
    {
        const float* srow = s + (size_t)r * CS;
        const float e0 = srow[t];
        const float e1 = (t < 128) ? srow[256 + t] : 0.f;
        float p = e0 + e1;
        #pragma unroll
        for (int m = 1; m < 64; m <<= 1) p += __shfl_xor(p, m);
        if (l == 0) red[w] = p;
        __syncthreads();
        const float mu = (red[0] + red[1] + red[2] + red[3]) * (1.0f / CS);
        __syncthreads();
        const float d0 = e0 - mu, d1 = e1 - mu;
        float q = d0 * d0 + ((t < 128) ? d1 * d1 : 0.f);
        #pragma unroll
        for (int m = 1; m < 64; m <<= 1) q += __shfl_xor(q, m);
        if (l == 0) red[w] = q;
        __syncthreads();
        const float var = (red[0] + red[1] + red[2] + red[3]) * (1.0f / CS);
        const float rstd = rsqrtf(var + EPS);
        sn[t] = d0 * rstd * g[t] + be[t];
        if (t < 128) sn[256 + t] = d1 * rstd * g[256 + t] + be[256 + t];
    }
    __syncthreads();

    // ---- a = sn @ W1 + b1 (8-way c-split) ----
    {
        const int h = t & 31, cs = t >> 5;
        float acc = 0.f;
        const int c0 = cs * 48;
        #pragma unroll 8
        for (int c = c0; c < c0 + 48; ++c)
            acc += sn[c] * W1[c * CH + h];
        part[cs][h] = acc;
    }
    __syncthreads();
    if (t < 32) {
        float a = pb1[t];
        #pragma unroll
        for (int k = 0; k < 8; ++k) a += part[k][t];
        Afl[t] = a;
    }
    __syncthreads();

    // ---- M = a @ Wo (col-major v4f, Wo read once per block from L2) ----
    {
        const v4f* Wo4 = (const v4f*)Wo;   // 1024 v4f per c-row
        #pragma unroll
        for (int it = 0; it < 4; ++it) {
            const int col = t + it * 256;
            v4f acc = (v4f)(0.f);
            #pragma unroll 8
            for (int c = 0; c < CH; ++c)
                acc += Afl[c] * Wo4[(size_t)c * 1024 + col];
            *(v4f*)&Msub[col * 4] = acc;
        }
    }
    __syncthreads();

    // ---- build mf[8] per lane from Msub ----
    s8v mf[8];
    #pragma unroll
    for (int zt = 0; zt < 8; ++zt) {
        u8s o;
        #pragma unroll
        for (int e = 0; e < 8; ++e)
            o[e] = f2bf(Msub[(g2 * 8 + e) * 128 + zt * 16 + c16]);
        mf[zt] = (s8v)o;
    }

    // ---- af + bias ----
    s8v af[6];
    {
        const s8v* Bfn = (const s8v*)(BfG + (size_t)n * 24 * 64 * 8);
        #pragma unroll
        for (int i = 0; i < 6; ++i) af[i] = Bfn[(w + i * 4) * 64 + l];
    }
    v4f bov[8];
    #pragma unroll
    for (int zt = 0; zt < 8; ++zt) bov[zt] = *(const v4f*)(bo + zt * 16 + g2 * 4);

    char* myl = (char*)bounce[w];
    v4f* outv = (v4f*)(out + (size_t)r * LL * CZ);   // 32 v4f per j-row

    #pragma unroll
    for (int i = 0; i < 6; ++i) {
        const int jt = w + i * 4;

        #pragma unroll
        for (int zt = 0; zt < 8; ++zt) {
            v4f d = __builtin_amdgcn_mfma_f32_16x16x32_bf16(mf[zt], af[i], (v4f)(0.f), 0, 0, 0);
            d += bov[zt];
            const int byte = (c16 << 9) + (((zt << 6) + (g2 << 4)) ^ ((c16 & 7) << 4));
            *(v4f*)(myl + byte) = d;
        }
        asm volatile("s_waitcnt lgkmcnt(0)" ::: "memory");

        #pragma unroll
        for (int i2 = 0; i2 < 8; ++i2) {
            const int rw2 = 2 * i2 + hi2;
            const int byte = (rw2 << 9) + (((li << 4)) ^ ((rw2 & 7) << 4));
            const v4f v = *(const v4f*)(myl + byte);
            outv[(size_t)(jt * 16 + rw2) * 32 + li] = v;
        }
    }
}

extern "C" void kernel_launch(void* const* d_in, const int* in_sizes, int n_in,
                              void* d_out, int out_size, void* d_ws, size_t ws_size,
                              hipStream_t stream) {
    const float* s  = (const float*)d_in[0];
    const float* g  = (const float*)d_in[1];
    const float* be = (const float*)d_in[2];
    const float* W1 = (const float*)d_in[3];
    const float* b1 = (const float*)d_in[4];
    const float* W2 = (const float*)d_in[5];
    const float* b2 = (const float*)d_in[6];
    const float* Wo = (const float*)d_in[7];
    const float* bo = (const float*)d_in[8];
    float* out = (float*)d_out;

    // ws layout (bytes): Bf bf16 [0, 98304)
    if (ws_size < 98304u) return;  // fail visibly, no UB
    unsigned short* Bf = (unsigned short*)d_ws;

    k_bf   <<<NL / 4, 256, 0, stream>>>(s, g, be, W2, b2, Bf);
    k_out_f<<<NL, 256, 0, stream>>>(s, g, be, W1, b1, Wo, Bf, bo, out);
}

// Round 21
// 81.005 us; speedup vs baseline: 2.5450x; 1.0561x over previous
//
#include <hip/hip_runtime.h>
#include <hip/hip_bf16.h>

#define CS 384
#define CH 32
#define CZ 128
#define LL 384
#define NL 1536   // N*L
#define EPS 1e-5f

typedef float v4f __attribute__((ext_vector_type(4)));
typedef short s8v __attribute__((ext_vector_type(8)));          // 8 bf16 (MFMA A/B frag)
typedef unsigned short u8s __attribute__((ext_vector_type(8))); // 8 bf16 bits

static __device__ __forceinline__ unsigned short f2bf(float x) {
    unsigned int b = __float_as_uint(x);
    b += 0x7FFFu + ((b >> 16) & 1u);        // round-to-nearest-even
    return (unsigned short)(b >> 16);
}
static __device__ __forceinline__ v4f bf4_to_f4(ushort4 h) {
    v4f r;
    r.x = __uint_as_float((unsigned)h.x << 16);
    r.y = __uint_as_float((unsigned)h.y << 16);
    r.z = __uint_as_float((unsigned)h.z << 16);
    r.w = __uint_as_float((unsigned)h.w << 16);
    return r;
}

// ---------------- Kernel 1: LN + B = sn@W2+b2 -> Bf frags; Wo -> bf16 --------
// 384 blocks x 256 thr, 4 rows/block (identical to R20 k_bf) + blocks 0..127
// convert Wo (512 KB fp32) to Wob (256 KB bf16, stays L2-resident).
__global__ __launch_bounds__(256) void k_bf(
    const float* __restrict__ s, const float* __restrict__ g, const float* __restrict__ be,
    const float* __restrict__ W2, const float* __restrict__ pb2,
    const float* __restrict__ Wo,
    unsigned short* __restrict__ BfG, unsigned short* __restrict__ Wob)
{
    const int r0 = blockIdx.x * 4;
    const int t  = threadIdx.x;

    // Wo conversion: one v4f -> ushort4 per thread for idx < 32768
    {
        const int idx = blockIdx.x * 256 + t;
        if (idx < (CH * CH * CZ) / 4) {
            const v4f v = ((const v4f*)Wo)[idx];
            ushort4 h;
            h.x = f2bf(v.x); h.y = f2bf(v.y); h.z = f2bf(v.z); h.w = f2bf(v.w);
            ((ushort4*)Wob)[idx] = h;
        }
    }

    __shared__ float sn[4][392];
    __shared__ float part[4][2][32];

    // LN, wave per row
    {
        const int w = t >> 6, lane = t & 63;
        const float* srow = s + (size_t)(r0 + w) * CS;
        float x[6];
        #pragma unroll
        for (int k = 0; k < 6; ++k) x[k] = srow[lane + k * 64];
        float p = x[0] + x[1] + x[2] + x[3] + x[4] + x[5];
        #pragma unroll
        for (int m = 1; m < 64; m <<= 1) p += __shfl_xor(p, m);
        const float mu = p * (1.0f / CS);
        float q = 0.f;
        #pragma unroll
        for (int k = 0; k < 6; ++k) { float d = x[k] - mu; q += d * d; }
        #pragma unroll
        for (int m = 1; m < 64; m <<= 1) q += __shfl_xor(q, m);
        const float rstd = rsqrtf(q * (1.0f / CS) + EPS);
        #pragma unroll
        for (int k = 0; k < 6; ++k) {
            const int c = lane + k * 64;
            sn[w][c] = (x[k] - mu) * rstd * g[c] + be[c];
        }
    }
    __syncthreads();

    // matvec W2, c-halves
    {
        const int h = t & 31, ch = (t >> 5) & 1, rw = t >> 6;
        const float* snr = sn[rw];
        float acc = 0.f;
        const int c0 = ch * 192;
        #pragma unroll 8
        for (int c = c0; c < c0 + 192; ++c)
            acc += snr[c] * W2[c * CH + h];
        part[rw][ch][h] = acc;
    }
    __syncthreads();

    if (t < 128) {
        const int rw = t >> 5, h = t & 31;
        const float v = part[rw][0][h] + part[rw][1][h] + pb2[h];
        const int row = r0 + rw;
        const int n = row / LL, jr = row % LL;
        const int jt = jr >> 4, l16 = jr & 15;
        BfG[(((size_t)(n * 24 + jt)) * 64 + l16 + 16 * (h >> 3)) * 8 + (h & 7)] = f2bf(v);
    }
}

// ---------------- Kernel 2: r-pair fused prep + MFMA out ---------------------
// Grid 768 x 256 (3 blocks/CU, 48 KB LDS). Block owns rows {2b, 2b+1}:
// LN -> a-matvec -> M = a@Wob (bf16 Wo, 256 KB/block from L2-resident copy)
// -> MsubT bf16 TRANSPOSED [rr][z*32+d] (mf rebuild = 1 ds_read_b128/(rr,zt))
// -> R16's exact out loop. LDS overlay: MsubT 16 KB persistent; bounce 32 KB
// overlays sn/part/Afl after prep.
__global__ __launch_bounds__(256, 3) void k_out_f(
    const float* __restrict__ s, const float* __restrict__ g, const float* __restrict__ be,
    const float* __restrict__ W1, const float* __restrict__ pb1,
    const unsigned short* __restrict__ Wob, const unsigned short* __restrict__ BfG,
    const float* __restrict__ bo, float* __restrict__ out)
{
    const int b  = blockIdx.x;      // 0..767
    const int r0 = b * 2;
    const int n  = r0 / LL;
    const int t  = threadIdx.x;
    const int l = t & 63, w = t >> 6;
    const int g2 = l >> 4, c16 = l & 15;
    const int li = l & 31, hi2 = l >> 5;

    __shared__ __align__(16) char smem[16384 + 32768];   // 48 KB
    unsigned short* MsubT = (unsigned short*)smem;        // [2][4096]: [rr][z*32+d]
    float (*sn)[392]      = (float(*)[392])(smem + 16384);           // 3136 B
    float (*part)[4][32]  = (float(*)[4][32])(smem + 16384 + 3200);  // 1024 B
    float* Afl            = (float*)(smem + 16384 + 3200 + 1024);    // [2][32]
    char*  bounceBase     = smem + 16384;                 // out-phase overlay (32 KB)

    // ---- LN rows r0, r0+1 (waves 0,1) ----
    if (w < 2) {
        const float* srow = s + (size_t)(r0 + w) * CS;
        float x[6];
        #pragma unroll
        for (int k = 0; k < 6; ++k) x[k] = srow[l + k * 64];
        float p = x[0] + x[1] + x[2] + x[3] + x[4] + x[5];
        #pragma unroll
        for (int m = 1; m < 64; m <<= 1) p += __shfl_xor(p, m);
        const float mu = p * (1.0f / CS);
        float q = 0.f;
        #pragma unroll
        for (int k = 0; k < 6; ++k) { float d = x[k] - mu; q += d * d; }
        #pragma unroll
        for (int m = 1; m < 64; m <<= 1) q += __shfl_xor(q, m);
        const float rstd = rsqrtf(q * (1.0f / CS) + EPS);
        #pragma unroll
        for (int k = 0; k < 6; ++k) {
            const int c = l + k * 64;
            sn[w][c] = (x[k] - mu) * rstd * g[c] + be[c];
        }
    }
    __syncthreads();

    // ---- a = sn@W1 + b1, both rows: h=t&31, cs=(t>>5)&3, rw=t>>7 ----
    {
        const int h = t & 31, cs = (t >> 5) & 3, rw = t >> 7;
        const float* snr = sn[rw];
        float acc = 0.f;
        const int c0 = cs * 96;
        #pragma unroll 8
        for (int c = c0; c < c0 + 96; ++c)
            acc += snr[c] * W1[c * CH + h];
        part[rw][cs][h] = acc;
    }
    __syncthreads();
    if (t < 64) {
        const int rw = t >> 5, h = t & 31;
        Afl[rw * 32 + h] = part[rw][0][h] + part[rw][1][h] + part[rw][2][h]
                         + part[rw][3][h] + pb1[h];
    }
    __syncthreads();

    // ---- M = a @ Wob (bf16), both rows -> MsubT (transposed, bf16) ----
    {
        const ushort4* Wo4 = (const ushort4*)Wob;   // 1024 ushort4 per c-row
        #pragma unroll
        for (int it = 0; it < 4; ++it) {
            const int col = t + it * 256;           // col = d*32 + zq
            const int d = col >> 5, zq = col & 31;  // z = zq*4 + j
            v4f a0 = (v4f)(0.f), a1 = (v4f)(0.f);
            #pragma unroll 8
            for (int c = 0; c < CH; ++c) {
                const v4f wv = bf4_to_f4(Wo4[(size_t)c * 1024 + col]);
                a0 += Afl[c] * wv;
                a1 += Afl[32 + c] * wv;
            }
            #pragma unroll
            for (int j = 0; j < 4; ++j) {
                const int z = zq * 4 + j;
                MsubT[z * 32 + d]        = f2bf(a0[j]);
                MsubT[4096 + z * 32 + d] = f2bf(a1[j]);
            }
        }
    }
    __syncthreads();   // MsubT ready; prep overlay region now free for bounce

    // ---- af + bias ----
    s8v af[6];
    {
        const s8v* Bfn = (const s8v*)(BfG + (size_t)n * 24 * 64 * 8);
        #pragma unroll
        for (int i = 0; i < 6; ++i) af[i] = Bfn[(w + i * 4) * 64 + l];
    }
    v4f bov[8];
    #pragma unroll
    for (int zt = 0; zt < 8; ++zt) bov[zt] = *(const v4f*)(bo + zt * 16 + g2 * 4);

    char* myl = bounceBase + w * 8192;

    #pragma unroll
    for (int rr = 0; rr < 2; ++rr) {
        // mf rebuild: one b128 LDS read per zt (contiguous 8 bf16 along d)
        s8v mf[8];
        {
            const unsigned short* Ms = MsubT + rr * 4096;
            #pragma unroll
            for (int zt = 0; zt < 8; ++zt)
                mf[zt] = *(const s8v*)(Ms + (zt * 16 + c16) * 32 + g2 * 8);
        }

        v4f* outv = (v4f*)(out + (size_t)(r0 + rr) * LL * CZ);

        #pragma unroll
        for (int i = 0; i < 6; ++i) {
            const int jt = w + i * 4;

            #pragma unroll
            for (int zt = 0; zt < 8; ++zt) {
                v4f d = __builtin_amdgcn_mfma_f32_16x16x32_bf16(mf[zt], af[i], (v4f)(0.f), 0, 0, 0);
                d += bov[zt];
                const int byte = (c16 << 9) + (((zt << 6) + (g2 << 4)) ^ ((c16 & 7) << 4));
                *(v4f*)(myl + byte) = d;
            }
            asm volatile("s_waitcnt lgkmcnt(0)" ::: "memory");

            #pragma unroll
            for (int i2 = 0; i2 < 8; ++i2) {
                const int rw2 = 2 * i2 + hi2;
                const int byte = (rw2 << 9) + (((li << 4)) ^ ((rw2 & 7) << 4));
                const v4f v = *(const v4f*)(myl + byte);
                outv[(size_t)(jt * 16 + rw2) * 32 + li] = v;
            }
        }
        __syncthreads();   // bounce reuse across rr
    }
}

extern "C" void kernel_launch(void* const* d_in, const int* in_sizes, int n_in,
                              void* d_out, int out_size, void* d_ws, size_t ws_size,
                              hipStream_t stream) {
    const float* s  = (const float*)d_in[0];
    const float* g  = (const float*)d_in[1];
    const float* be = (const float*)d_in[2];
    const float* W1 = (const float*)d_in[3];
    const float* b1 = (const float*)d_in[4];
    const float* W2 = (const float*)d_in[5];
    const float* b2 = (const float*)d_in[6];
    const float* Wo = (const float*)d_in[7];
    const float* bo = (const float*)d_in[8];
    float* out = (float*)d_out;

    // ws layout (bytes): Bf bf16 [0, 98304) | Wob bf16 [98304, 98304+262144)
    if (ws_size < 98304u + 262144u) return;  // fail visibly, no UB
    unsigned short* Bf  = (unsigned short*)d_ws;
    unsigned short* Wob = (unsigned short*)((char*)d_ws + 98304);

    k_bf   <<<NL / 4, 256, 0, stream>>>(s, g, be, W2, b2, Wo, Bf, Wob);
    k_out_f<<<NL / 2, 256, 0, stream>>>(s, g, be, W1, b1, Wob, Bf, bo, out);
}